// Round 11
// baseline (22056.485 us; speedup 1.0000x reference)
//
#include <hip/hip_runtime.h>

typedef __bf16 bf16x8 __attribute__((ext_vector_type(8)));
typedef float f32x4 __attribute__((ext_vector_type(4)));
typedef unsigned short u16;
typedef unsigned int u32;
typedef u16 u16x8 __attribute__((ext_vector_type(8)));

#define MFMA16(a, b, c) __builtin_amdgcn_mfma_f32_16x16x32_bf16((a), (b), (c), 0, 0, 0)

// ---------------------------------------------------------------------------
// R10 structure (proven 22.0ms) + group-local t-loop barriers.
// Grid 256x256: bid<128 = half0, bid>=128 = half1; rt=(bid&127)>>4,
// cb=(bid&15)*4+wid. Row-group rt = 32 blocks (16 half0 + 16 half1) — ALL
// producer/consumer pairs in the t-loop are within one group, so per-round
// sync is a per-group flat 32-participant AGENT epoch counter (own LLC line,
// memset-zeroed, replay-safe). Groups drift independently. Prologue (hygiene,
// P0 weights) keeps the global hierarchical barrier.
// States: sc0sc1 LLC ops, 16B-vectorized via per-wave LDS transpose.
// Weights: plain cached reads after sc1 init + one-time wbl2/inv hygiene.
//
// Per step (5 group barriers):
//  A: half0 s0=f(W0@[x|h]) -> slot1
//  B: half0 s1 (sig)       -> slot2, reg rs1
//  C: half0 s2(relu)->slot3+rs2, s4(ident) reg-only; half1 s3(relu)->slot4
//  D: half0 s5(tanh on s2)->slot5+rs5;          half1 s7(tanh on s3)->slot6
//  E: half0 s6(sig),s8(relu) reg; mean(rs*,s3,s7 vec-read) -> out, h->slot0
//
// counters (4096B memset 0): gbar sub c*64 (c<8), top 512; group rt counter
//   at 576+rt*16 (64B apart, all < 1024).
// ws u16: Wh[5242880] @ byte 4096, Wl[5242880], S[7][131072]: slots
//   0=h 1=s0 2=s1 3=s2 4=s3 5=s5 6=s7 (per (slot,rt): hi[8192]++lo[8192]).
// ---------------------------------------------------------------------------

__device__ __forceinline__ u16 f2bf(float f) {
  u32 u = __float_as_uint(f);
  u += 0x7FFFu + ((u >> 16) & 1u);
  return (u16)(u >> 16);
}
__device__ __forceinline__ float bf2f(u32 h) { return __uint_as_float(h << 16); }
__device__ __forceinline__ void splitbf(float f, u16 &hi, u16 &lo) {
  hi = f2bf(f);
  lo = f2bf(f - bf2f((u32)hi));
}

__device__ __forceinline__ void issue_ld128_sc(bf16x8 &d, const u16 *p) {
  asm volatile("global_load_dwordx4 %0, %1, off sc0 sc1" : "=v"(d) : "v"(p));
}
__device__ __forceinline__ void issue_ld128u_sc(u16x8 &d, const u16 *p) {
  asm volatile("global_load_dwordx4 %0, %1, off sc0 sc1" : "=v"(d) : "v"(p));
}
__device__ __forceinline__ void st128_sc(u16 *p, u16x8 v) {
  asm volatile("global_store_dwordx4 %0, %1, off sc0 sc1" :: "v"(p), "v"(v) : "memory");
}
__device__ __forceinline__ void st16_sc(u16 *p, u16 v) {
  u32 q = v;
  asm volatile("global_store_short %0, %1, off sc0 sc1" :: "v"(p), "v"(q) : "memory");
}
__device__ __forceinline__ void wait_vm() {
  asm volatile("s_waitcnt vmcnt(0)" ::: "memory");
  __builtin_amdgcn_sched_barrier(0);
}
// counted waits for the staged-load ladder (entered with vmcnt==0 only!)
__device__ __forceinline__ void wait_vm_n(int n) {
  switch (n) {
    case 0: asm volatile("s_waitcnt vmcnt(0)" ::: "memory"); break;
    case 1: asm volatile("s_waitcnt vmcnt(1)" ::: "memory"); break;
    case 2: asm volatile("s_waitcnt vmcnt(2)" ::: "memory"); break;
    case 3: asm volatile("s_waitcnt vmcnt(3)" ::: "memory"); break;
    case 4: asm volatile("s_waitcnt vmcnt(4)" ::: "memory"); break;
    case 5: asm volatile("s_waitcnt vmcnt(5)" ::: "memory"); break;
    case 6: asm volatile("s_waitcnt vmcnt(6)" ::: "memory"); break;
    default: asm volatile("s_waitcnt vmcnt(7)" ::: "memory"); break;
  }
  __builtin_amdgcn_sched_barrier(0);
}

__device__ __forceinline__ int mbase(int m) {          // u16 elems; m=0 -> W0 (K=1024)
  return m == 0 ? 0 : 1048576 + (m - 1) * 524288;
}
__device__ __forceinline__ int lineOf(int row15, int scol) {
  return (scol >> 5) * 64 + row15 + ((scol >> 3) & 3) * 16;
}
__device__ __forceinline__ int goff(int slot, int row, int scol) {  // hi; lo at +8192
  return slot * 131072 + (row >> 4) * 16384 + lineOf(row & 15, scol) * 8 + (scol & 7);
}

template <int A> __device__ __forceinline__ float actf(float x) {
  if (A == 0) { float e = __expf(2.f * x); return 1.f - 2.f / (e + 1.f); } // tanh
  if (A == 1) return 1.f / (1.f + __expf(-x));                            // sigmoid
  if (A == 2) return fmaxf(x, 0.f);                                       // relu
  return x;                                                               // identity
}

__device__ __forceinline__ float lds_elem(const u16 *lds, int row15, int scol) {
  int o = lineOf(row15, scol) * 8 + (scol & 7);
  return bf2f(lds[o]) + bf2f(lds[o + 8192]);
}

// staged copy, counted-vmcnt ladder: ONLY when no other VMEM is outstanding
__device__ __forceinline__ void stage_panel_cw(const u16 *S, int slot, int rt, u16 *lds, int tid) {
  const u16 *src = S + slot * 131072 + rt * 16384 + tid * 8;
  bf16x8 r[8];
#pragma unroll
  for (int i = 0; i < 8; ++i) issue_ld128_sc(r[i], src + i * 2048);
#pragma unroll
  for (int i = 0; i < 8; ++i) {
    wait_vm_n(7 - i);
    *(bf16x8 *)(lds + tid * 8 + i * 2048) = r[i];
  }
}
// full-drain variant (safe with concurrent outstanding VMEM, e.g. E prefetch)
__device__ __forceinline__ void stage_panel_drain(const u16 *S, int slot, int rt, u16 *lds, int tid) {
  const u16 *src = S + slot * 131072 + rt * 16384 + tid * 8;
  bf16x8 r[8];
#pragma unroll
  for (int i = 0; i < 8; ++i) issue_ld128_sc(r[i], src + i * 2048);
  wait_vm();
#pragma unroll
  for (int i = 0; i < 8; ++i) *(bf16x8 *)(lds + tid * 8 + i * 2048) = r[i];
}

// activation only (no store)
template <int ACT>
__device__ __forceinline__ void act_only(f32x4 acc, const float *spv, float *sv) {
#pragma unroll
  for (int j = 0; j < 4; ++j) {
    float cp = acc[j];
    float hp = __shfl_xor(cp, 1);
    float sig = 1.f / (1.f + __expf(-cp));
    sv[j] = spv[j] + sig * (actf<ACT>(hp) - spv[j]);
  }
}

// vectorized state store: frag-layout sv -> per-wave LDS transpose -> 2x16B/row
__device__ __forceinline__ void store_state(const float *sv, u16 *S, int dslot,
                                            int rt, int cb, float *fscrw,
                                            int ln, int l4, int l15) {
  if ((l15 & 1) == 0) {
#pragma unroll
    for (int j = 0; j < 4; ++j) fscrw[(l4 * 4 + j) * 8 + (l15 >> 1)] = sv[j];
  }
  if (ln < 16) {
    u16x8 H, L;
#pragma unroll
    for (int c = 0; c < 8; ++c) {
      u16 hi, lo;
      splitbf(fscrw[ln * 8 + c], hi, lo);
      H[c] = hi; L[c] = lo;
    }
    u16 *p = S + goff(dslot, rt * 16 + ln, cb * 8);
    st128_sc(p, H);
    st128_sc(p + 8192, L);
  }
}

// K=512 GEMM; A-panel + s_prev from LDS; weights plain cached loads; no store
template <int ACT0, int ACT1, bool TWO>
__device__ __forceinline__ void gemm512(const u16 *Wh, const u16 *Wl, const u16 *lds,
                                        int m0, int m1, int cb, int ln, int l4, int l15,
                                        float *sv0, float *sv1) {
  float spv[4];
#pragma unroll
  for (int j = 0; j < 4; ++j) spv[j] = lds_elem(lds, l4 * 4 + j, cb * 8 + (l15 >> 1));
  f32x4 acc0 = {0.f, 0.f, 0.f, 0.f}, acc1 = {0.f, 0.f, 0.f, 0.f};
  const u16 *w0h = Wh + mbase(m0) + (cb * 16 * 64 + ln) * 8;
  const u16 *w0l = Wl + mbase(m0) + (cb * 16 * 64 + ln) * 8;
  const u16 *w1h = Wh + mbase(m1) + (cb * 16 * 64 + ln) * 8;
  const u16 *w1l = Wl + mbase(m1) + (cb * 16 * 64 + ln) * 8;
#pragma unroll
  for (int kc = 0; kc < 16; ++kc) {
    bf16x8 Ah = *(const bf16x8 *)(lds + (kc * 64 + ln) * 8);
    bf16x8 Al = *(const bf16x8 *)(lds + 8192 + (kc * 64 + ln) * 8);
    bf16x8 b0h = *(const bf16x8 *)(w0h + kc * 512);
    bf16x8 b0l = *(const bf16x8 *)(w0l + kc * 512);
    acc0 = MFMA16(Ah, b0h, acc0);
    acc0 = MFMA16(Ah, b0l, acc0);
    acc0 = MFMA16(Al, b0h, acc0);
    if (TWO) {
      bf16x8 b1h = *(const bf16x8 *)(w1h + kc * 512);
      bf16x8 b1l = *(const bf16x8 *)(w1l + kc * 512);
      acc1 = MFMA16(Ah, b1h, acc1);
      acc1 = MFMA16(Ah, b1l, acc1);
      acc1 = MFMA16(Al, b1h, acc1);
    }
  }
  float spv2[4];
#pragma unroll
  for (int j = 0; j < 4; ++j) spv2[j] = spv[j];
  act_only<ACT0>(acc0, spv, sv0);
  if (TWO) act_only<ACT1>(acc1, spv2, sv1);
}

// round A: s0 = h + sigmoid(c)*(tanh(h') - h); A = [x_t | h], K=1024, W0.
__device__ __forceinline__ void roundA(const float *xin, int t, const u16 *Wh, const u16 *Wl,
                                       const u16 *lds, int rt, int cb, int ln, int l4, int l15,
                                       float *sv) {
  float spv[4];
#pragma unroll
  for (int j = 0; j < 4; ++j) spv[j] = lds_elem(lds, l4 * 4 + j, cb * 8 + (l15 >> 1));
  f32x4 acc = {0.f, 0.f, 0.f, 0.f};
  const u16 *wh = Wh + (cb * 32 * 64 + ln) * 8;
  const u16 *wl = Wl + (cb * 32 * 64 + ln) * 8;
  const float *xp = xin + (t * 128 + rt * 16 + l15) * 512 + l4 * 8;
#pragma unroll
  for (int kc = 0; kc < 16; ++kc) {  // x half (k<512), on-the-fly hi/lo split
    f32x4 xa = *(const f32x4 *)(xp + kc * 32);
    f32x4 xb = *(const f32x4 *)(xp + kc * 32 + 4);
    union { u16 u[8]; bf16x8 v; } H, Lo;
#pragma unroll
    for (int e = 0; e < 4; ++e) {
      splitbf(xa[e], H.u[e], Lo.u[e]);
      splitbf(xb[e], H.u[4 + e], Lo.u[4 + e]);
    }
    bf16x8 bh = *(const bf16x8 *)(wh + kc * 512);
    bf16x8 bl = *(const bf16x8 *)(wl + kc * 512);
    acc = MFMA16(H.v, bh, acc);
    acc = MFMA16(H.v, bl, acc);
    acc = MFMA16(Lo.v, bh, acc);
  }
#pragma unroll
  for (int kc = 0; kc < 16; ++kc) {  // h half (k>=512), from staged LDS
    bf16x8 Ah = *(const bf16x8 *)(lds + (kc * 64 + ln) * 8);
    bf16x8 Al = *(const bf16x8 *)(lds + 8192 + (kc * 64 + ln) * 8);
    bf16x8 bh = *(const bf16x8 *)(wh + (16 + kc) * 512);
    bf16x8 bl = *(const bf16x8 *)(wl + (16 + kc) * 512);
    acc = MFMA16(Ah, bh, acc);
    acc = MFMA16(Ah, bl, acc);
    acc = MFMA16(Al, bh, acc);
  }
  act_only<0>(acc, spv, sv);
}

// global hierarchical epoch barrier (prologue only), bounded polls
__device__ __forceinline__ void gbar(u32 *cnt, u32 &ep, u32 &pb) {
  wait_vm();
  __syncthreads();
  ep += 256u;
  if (threadIdx.x == 0) {
    const int c = blockIdx.x & 7;
    u32 old = __hip_atomic_fetch_add(&cnt[c * 64], 1u, __ATOMIC_RELAXED, __HIP_MEMORY_SCOPE_AGENT);
    if (((old + 1u) & 31u) == 0u)
      __hip_atomic_fetch_add(&cnt[512], 32u, __ATOMIC_RELAXED, __HIP_MEMORY_SCOPE_AGENT);
    bool ok = false;
    for (u32 i = 0; i < pb; ++i) {
      u32 v = __hip_atomic_load(&cnt[512], __ATOMIC_RELAXED, __HIP_MEMORY_SCOPE_AGENT);
      if ((int)(v - ep) >= 0) { ok = true; break; }
      __builtin_amdgcn_s_sleep(2);
    }
    if (!ok) pb = 4096u;
  }
  __syncthreads();
}

// per-group flat epoch barrier: 32 participants, one LLC line, bounded polls
__device__ __forceinline__ void grbar(u32 *gc, u32 &gep, u32 &pb) {
  wait_vm();   // drain this wave's sc-stores to LLC before arrival
  __syncthreads();
  gep += 32u;
  if (threadIdx.x == 0) {
    __hip_atomic_fetch_add(gc, 1u, __ATOMIC_RELAXED, __HIP_MEMORY_SCOPE_AGENT);
    bool ok = false;
    for (u32 i = 0; i < pb; ++i) {
      u32 v = __hip_atomic_load(gc, __ATOMIC_RELAXED, __HIP_MEMORY_SCOPE_AGENT);
      if ((int)(v - gep) >= 0) { ok = true; break; }
      __builtin_amdgcn_s_sleep(1);
    }
    if (!ok) pb = 4096u;
  }
  __syncthreads();
}

__global__ __launch_bounds__(256, 1) void darts_rnn(
    const float *__restrict__ xin, const float *__restrict__ h0in,
    const float *__restrict__ W0, const float *__restrict__ Wsi,
    float *__restrict__ out, u16 *__restrict__ wsu) {
  __shared__ u16 smem[16384];      // 32KB staging panel
  __shared__ float fscr[4][128];   // per-wave transpose scratch
  u32 *cnt = (u32 *)wsu;
  u16 *Wh = wsu + 2048;            // byte 4096
  u16 *Wl = Wh + 5242880;
  u16 *S = Wl + 5242880;

  const int tid = threadIdx.x, bid = blockIdx.x;
  const int ln = tid & 63, wid = tid >> 6;
  const int l15 = ln & 15, l4 = ln >> 4;
  const int rt = (bid & 127) >> 4;
  const int cb = (bid & 15) * 4 + wid;
  float *fscrw = fscr[wid];
  u32 *gc = cnt + 576 + rt * 16;   // group counter, own 64B line

  u32 ep = 0, pb = 1u << 22;

  // ---- hygiene: flush dirty ws lines (poison), then invalidate L2 ----
  if (wid == 0) asm volatile("buffer_wbl2 sc1" ::: "memory");
  wait_vm();
  gbar(cnt, ep, pb);
  if (wid == 0) asm volatile("buffer_inv sc1" ::: "memory");
  wait_vm();
  gbar(cnt, ep, pb);

  // ---- P0: weight hi/lo split into fragment layout ----
  for (int idx = bid * 256 + tid; idx < 5242880; idx += 65536) {
    int mk = idx >> 10, oc = idx & 1023;
    int m, k;
    if (mk < 1024) { m = 0; k = mk; } else { m = 1 + ((mk - 1024) >> 9); k = (mk - 1024) & 511; }
    float v = (m == 0) ? W0[k * 1024 + oc] : Wsi[((m - 1) * 512 + k) * 1024 + oc];
    int colp = (oc < 512) ? (oc * 2) : ((oc - 512) * 2 + 1);  // interleave c,h cols
    int cbw = colp >> 4;
    int kc = k >> 5;
    int lnn = (colp & 15) + ((k >> 3) & 3) * 16;
    int el = k & 7;
    int lineBase = (m == 0) ? (cbw * 32 + kc) : (cbw * 16 + kc);  // W0: K=1024
    int e = mbase(m) + (lineBase * 64 + lnn) * 8 + el;
    u16 hi, lo; splitbf(v, hi, lo);
    st16_sc(Wh + e, hi);
    st16_sc(Wl + e, lo);
  }
  {  // h0 -> slot 0
    int g = bid * 256 + tid;         // 65536 = 128*512
    int row = g >> 9, k = g & 511;
    u16 hi, lo; splitbf(h0in[g], hi, lo);
    int o = goff(0, row, k);
    st16_sc(S + o, hi);
    st16_sc(S + o + 8192, lo);
  }
  gbar(cnt, ep, pb);

  u32 gep = 0;
  for (int t = 0; t < 256; ++t) {
    float rs1[4], rs2[4], rs4[4], rs5[4], dum[4];
    // ---- round A: half0: s0 <- W0 @ [x_t | h] -> slot1 ----
    if (bid < 128) {
      stage_panel_cw(S, 0, rt, smem, tid);
      __syncthreads();
      float sv[4];
      roundA(xin, t, Wh, Wl, smem, rt, cb, ln, l4, l15, sv);
      store_state(sv, S, 1, rt, cb, fscrw, ln, l4, l15);
    }
    grbar(gc, gep, pb);
    // ---- round B: half0: s1 <- Ws0(sig) on s0 -> slot2, reg rs1 ----
    if (bid < 128) {
      stage_panel_cw(S, 1, rt, smem, tid);
      __syncthreads();
      gemm512<1, 1, false>(Wh, Wl, smem, 1, 1, cb, ln, l4, l15, rs1, dum);
      store_state(rs1, S, 2, rt, cb, fscrw, ln, l4, l15);
    }
    grbar(gc, gep, pb);
    // ---- round C: A = s1. half0: s2(relu)->slot3+rs2, s4(ident) reg;
    //                        half1: s3(relu)->slot4 ----
    stage_panel_cw(S, 2, rt, smem, tid);
    __syncthreads();
    if (bid < 128) {
      gemm512<2, 3, true>(Wh, Wl, smem, 2, 4, cb, ln, l4, l15, rs2, rs4);
      store_state(rs2, S, 3, rt, cb, fscrw, ln, l4, l15);
    } else {
      float sv[4];
      gemm512<2, 2, false>(Wh, Wl, smem, 3, 3, cb, ln, l4, l15, sv, dum);
      store_state(sv, S, 4, rt, cb, fscrw, ln, l4, l15);
    }
    grbar(gc, gep, pb);
    // ---- round D: half0: s5(tanh) on s2 -> slot5+rs5; half1: s7 on s3 -> slot6 ----
    stage_panel_cw(S, (bid < 128) ? 3 : 4, rt, smem, tid);
    __syncthreads();
    if (bid < 128) {
      gemm512<0, 0, false>(Wh, Wl, smem, 5, 5, cb, ln, l4, l15, rs5, dum);
      store_state(rs5, S, 5, rt, cb, fscrw, ln, l4, l15);
    } else {
      float sv[4];
      gemm512<0, 0, false>(Wh, Wl, smem, 7, 7, cb, ln, l4, l15, sv, dum);
      store_state(sv, S, 6, rt, cb, fscrw, ln, l4, l15);
    }
    grbar(gc, gep, pb);
    // ---- round E: half0: s6(sig),s8(relu) on s5; mean -> out, h -> slot0 ----
    if (bid < 128) {
      u16x8 p3h, p3l, p7h, p7l;
      if (ln < 16) {  // prefetch s3,s7 row-slices; latency hides under stage+gemm
        const u16 *p3 = S + goff(4, rt * 16 + ln, cb * 8);
        const u16 *p7 = S + goff(6, rt * 16 + ln, cb * 8);
        issue_ld128u_sc(p3h, p3);
        issue_ld128u_sc(p3l, p3 + 8192);
        issue_ld128u_sc(p7h, p7);
        issue_ld128u_sc(p7l, p7 + 8192);
      }
      stage_panel_drain(S, 5, rt, smem, tid);   // full drain covers prefetch
      __syncthreads();
      float sv6[4], sv8[4];
      gemm512<1, 2, true>(Wh, Wl, smem, 6, 8, cb, ln, l4, l15, sv6, sv8);
      if ((l15 & 1) == 0) {
#pragma unroll
        for (int j = 0; j < 4; ++j)
          fscrw[(l4 * 4 + j) * 8 + (l15 >> 1)] = rs1[j] + rs2[j] + rs4[j] + rs5[j] + sv6[j] + sv8[j];
      }
      if (ln < 16) {
        float o0[8];
        u16x8 H, L;
#pragma unroll
        for (int c = 0; c < 8; ++c) {
          float v = fscrw[ln * 8 + c];
          v += bf2f(p3h[c]) + bf2f(p3l[c]);
          v += bf2f(p7h[c]) + bf2f(p7l[c]);
          float hnew = v * 0.125f;
          o0[c] = hnew;
          u16 hi, lo; splitbf(hnew, hi, lo);
          H[c] = hi; L[c] = lo;
        }
        int row = rt * 16 + ln;
        float *op = out + t * 65536 + row * 512 + cb * 8;
        *(f32x4 *)op = *(f32x4 *)&o0[0];
        *(f32x4 *)(op + 4) = *(f32x4 *)&o0[4];
        if (t == 255) {
          float *op2 = out + 16777216 + row * 512 + cb * 8;
          *(f32x4 *)op2 = *(f32x4 *)&o0[0];
          *(f32x4 *)(op2 + 4) = *(f32x4 *)&o0[4];
        }
        u16 *p = S + goff(0, row, cb * 8);
        st128_sc(p, H);
        st128_sc(p + 8192, L);
      }
    }
    grbar(gc, gep, pb);
  }
}

extern "C" void kernel_launch(void *const *d_in, const int *in_sizes, int n_in,
                              void *d_out, int out_size, void *d_ws, size_t ws_size,
                              hipStream_t stream) {
  const float *x = (const float *)d_in[0];
  const float *h0 = (const float *)d_in[1];
  const float *W0 = (const float *)d_in[2];
  const float *Ws = (const float *)d_in[3];
  float *out = (float *)d_out;
  u16 *ws = (u16 *)d_ws;

  hipMemsetAsync(d_ws, 0, 4096, stream);  // zero barrier counters

  void *args[] = {(void *)&x, (void *)&h0, (void *)&W0, (void *)&Ws, (void *)&out, (void *)&ws};
  hipError_t err = hipLaunchCooperativeKernel((void *)darts_rnn, dim3(256), dim3(256),
                                              args, 0, stream);
  if (err != hipSuccess) {
    (void)hipGetLastError();
    darts_rnn<<<dim3(256), dim3(256), 0, stream>>>(x, h0, W0, Ws, out, ws);
  }
}